// Round 1
// baseline (236.456 us; speedup 1.0000x reference)
//
#include <hip/hip_runtime.h>
#include <hip/hip_bf16.h>
#include <math.h>

#define SELU_SCALE 1.0507009873554805f
#define SELU_ALPHA 1.6732632423543772f

static constexpr int B_ = 16, T_ = 16, L_ = 512, H_ = 768;

typedef __bf16 bf16x8 __attribute__((ext_vector_type(8)));
typedef float  f32x4  __attribute__((ext_vector_type(4)));

// ---------------- converts ----------------
__global__ void f32_to_bf16_k(const float* __restrict__ in, __bf16* __restrict__ out, int n) {
    int i = blockIdx.x * blockDim.x + threadIdx.x;
    int stride = gridDim.x * blockDim.x;
    for (; i < n; i += stride) out[i] = (__bf16)in[i];
}

// dj[bt,:] = decoder_out[b, Yindex[bt], :]  (converted to bf16)
__global__ void gather_dj_k(const float* __restrict__ dec, const int* __restrict__ Yi,
                            __bf16* __restrict__ djb) {
    int bt = blockIdx.x;
    int b  = bt >> 4;
    int y  = Yi[bt];
    const float* src = dec + ((size_t)b * L_ + y) * H_;
    __bf16* dst = djb + (size_t)bt * H_;
    for (int h = threadIdx.x; h < H_; h += blockDim.x) dst[h] = (__bf16)src[h];
}

// ---------------- NT GEMM: C[m][n] = sum_k A[m][k]*Bm[n][k], bf16 in, bf16 out ----
// block = 256 thr = 4 waves (2x2), wave tile 64x64 (4x4 MFMA 16x16x32), block tile 128x128.
// grid = (M/128, N/128). K multiple of 32.
__global__ __launch_bounds__(256) void gemm_nt_bf16_k(
        const __bf16* __restrict__ A, const __bf16* __restrict__ Bm,
        __bf16* __restrict__ C, int M, int N, int K) {
    const int wave = threadIdx.x >> 6;
    const int lane = threadIdx.x & 63;
    const int waveM = wave >> 1, waveN = wave & 1;
    const int m0 = blockIdx.x * 128 + waveM * 64;
    const int n0 = blockIdx.y * 128 + waveN * 64;
    const int lr = lane & 15;   // row (A) / col (B) within 16-tile
    const int q  = lane >> 4;   // quad: k offset q*8

    f32x4 acc[4][4] = {};

    const __bf16* Abase = A  + (size_t)(m0 + lr) * K + q * 8;
    const __bf16* Bbase = Bm + (size_t)(n0 + lr) * K + q * 8;

    for (int k0 = 0; k0 < K; k0 += 32) {
        bf16x8 af[4], bfr[4];
#pragma unroll
        for (int i = 0; i < 4; ++i)
            af[i] = *reinterpret_cast<const bf16x8*>(Abase + (size_t)i * 16 * K + k0);
#pragma unroll
        for (int j = 0; j < 4; ++j)
            bfr[j] = *reinterpret_cast<const bf16x8*>(Bbase + (size_t)j * 16 * K + k0);
#pragma unroll
        for (int i = 0; i < 4; ++i)
#pragma unroll
            for (int j = 0; j < 4; ++j)
                acc[i][j] = __builtin_amdgcn_mfma_f32_16x16x32_bf16(af[i], bfr[j], acc[i][j], 0, 0, 0);
    }

    // D[row = q*4+reg][col = lane&15] per 16x16 tile
#pragma unroll
    for (int i = 0; i < 4; ++i) {
#pragma unroll
        for (int j = 0; j < 4; ++j) {
#pragma unroll
            for (int r = 0; r < 4; ++r) {
                int row = m0 + i * 16 + q * 4 + r;
                int col = n0 + j * 16 + lr;
                C[(size_t)row * N + col] = (__bf16)acc[i][j][r];
            }
        }
    }
}

// ---------------- fused scores: scores[b][t][l] = selu(sum_g selu(WE+WD)*V) -------
// grid (B, L/16), 256 threads (4 waves, 4 l's each)
__global__ __launch_bounds__(256) void scores_k(
        const __bf16* __restrict__ web, const __bf16* __restrict__ wdb,
        const float* __restrict__ V, float* __restrict__ scores) {
    __shared__ float wd_s[T_ * H_];   // 48 KiB
    __shared__ float v_s[H_];         // 3 KiB

    const int b  = blockIdx.x;
    const int lc = blockIdx.y * 16;

    for (int idx = threadIdx.x; idx < T_ * H_; idx += blockDim.x)
        wd_s[idx] = (float)wdb[(size_t)b * T_ * H_ + idx];
    for (int idx = threadIdx.x; idx < H_; idx += blockDim.x)
        v_s[idx] = V[idx];
    __syncthreads();

    const int wave = threadIdx.x >> 6;
    const int lane = threadIdx.x & 63;

    float vr[12];
#pragma unroll
    for (int k = 0; k < 12; ++k) vr[k] = v_s[lane + 64 * k];

    for (int li = wave; li < 16; li += 4) {
        const int l = lc + li;
        const __bf16* wrow = web + ((size_t)b * L_ + l) * H_;
        float we[12];
#pragma unroll
        for (int k = 0; k < 12; ++k) we[k] = (float)wrow[lane + 64 * k];

        for (int t = 0; t < T_; ++t) {
            float s = 0.0f;
#pragma unroll
            for (int k = 0; k < 12; ++k) {
                float x = we[k] + wd_s[t * H_ + lane + 64 * k];
                float e = (x > 0.0f) ? x : SELU_ALPHA * (__expf(x) - 1.0f);
                s = fmaf(e, vr[k], s);
            }
#pragma unroll
            for (int off = 32; off > 0; off >>= 1) s += __shfl_xor(s, off);
            if (lane == 0) {
                float dot = SELU_SCALE * s;
                float sc  = (dot > 0.0f) ? SELU_SCALE * dot
                                         : SELU_SCALE * SELU_ALPHA * (__expf(dot) - 1.0f);
                scores[((size_t)b * T_ + t) * L_ + l] = sc;
            }
        }
    }
}

// ---------------- per-(b,t) masked logsumexp + gold ----------------
__global__ __launch_bounds__(64) void nll_k(
        const float* __restrict__ scores, const int* __restrict__ Xi,
        const int* __restrict__ Yi, float* __restrict__ gold) {
    const int bt = blockIdx.x;
    const int lane = threadIdx.x;
    const int X = Xi[bt];
    const int Y = Yi[bt];
    const float* row = scores + (size_t)bt * L_;

    float m = -INFINITY;
    for (int l = X + lane; l < L_; l += 64) m = fmaxf(m, row[l]);
#pragma unroll
    for (int off = 32; off > 0; off >>= 1) m = fmaxf(m, __shfl_xor(m, off));

    float s = 0.0f;
    for (int l = X + lane; l < L_; l += 64) s += expf(row[l] - m);
#pragma unroll
    for (int off = 32; off > 0; off >>= 1) s += __shfl_xor(s, off);

    if (lane == 0) gold[bt] = row[Y] - m - logf(s);
}

__global__ __launch_bounds__(256) void finalize_k(const float* __restrict__ gold,
                                                  float* __restrict__ out) {
    __shared__ float red[4];
    const int lane = threadIdx.x & 63, wave = threadIdx.x >> 6;
    float v = gold[threadIdx.x];
#pragma unroll
    for (int off = 32; off > 0; off >>= 1) v += __shfl_xor(v, off);
    if (lane == 0) red[wave] = v;
    __syncthreads();
    if (threadIdx.x == 0) out[0] = -(red[0] + red[1] + red[2] + red[3]) * (1.0f / 256.0f);
}

// ---------------- launch ----------------
extern "C" void kernel_launch(void* const* d_in, const int* in_sizes, int n_in,
                              void* d_out, int out_size, void* d_ws, size_t ws_size,
                              hipStream_t stream) {
    const float* hn  = (const float*)d_in[0];
    const float* dec = (const float*)d_in[1];
    const float* W1  = (const float*)d_in[2];
    const float* W2  = (const float*)d_in[3];
    const float* V   = (const float*)d_in[4];
    const int*   Xi  = (const int*)d_in[5];
    const int*   Yi  = (const int*)d_in[6];
    float* out = (float*)d_out;

    char* ws = (char*)d_ws;
    size_t off = 0;
    auto alloc = [&](size_t bytes) -> char* {
        char* p = ws + off;
        off += (bytes + 255) & ~(size_t)255;
        return p;
    };
    __bf16* hnb    = (__bf16*)alloc((size_t)B_ * L_ * H_ * 2);   // 12.6 MB
    __bf16* w1b    = (__bf16*)alloc((size_t)H_ * H_ * 2);
    __bf16* w2b    = (__bf16*)alloc((size_t)H_ * H_ * 2);
    __bf16* djb    = (__bf16*)alloc((size_t)B_ * T_ * H_ * 2);
    __bf16* web    = (__bf16*)alloc((size_t)B_ * L_ * H_ * 2);   // 12.6 MB
    __bf16* wdb    = (__bf16*)alloc((size_t)B_ * T_ * H_ * 2);
    float*  scores = (float*)alloc((size_t)B_ * T_ * L_ * 4);
    float*  gold   = (float*)alloc((size_t)B_ * T_ * 4);

    f32_to_bf16_k<<<1024, 256, 0, stream>>>(hn, hnb, B_ * L_ * H_);
    f32_to_bf16_k<<<256, 256, 0, stream>>>(W1, w1b, H_ * H_);
    f32_to_bf16_k<<<256, 256, 0, stream>>>(W2, w2b, H_ * H_);
    gather_dj_k<<<B_ * T_, 256, 0, stream>>>(dec, Yi, djb);

    // WE = hn @ W1^T : M=8192, N=768, K=768
    gemm_nt_bf16_k<<<dim3(64, 6), 256, 0, stream>>>(hnb, w1b, web, B_ * L_, H_, H_);
    // WD = dj @ W2^T : M=256, N=768, K=768
    gemm_nt_bf16_k<<<dim3(2, 6), 256, 0, stream>>>(djb, w2b, wdb, B_ * T_, H_, H_);

    scores_k<<<dim3(B_, L_ / 16), 256, 0, stream>>>(web, wdb, V, scores);
    nll_k<<<B_ * T_, 64, 0, stream>>>(scores, Xi, Yi, gold);
    finalize_k<<<1, 256, 0, stream>>>(gold, out);
}

// Round 2
// 177.680 us; speedup vs baseline: 1.3308x; 1.3308x over previous
//
#include <hip/hip_runtime.h>
#include <hip/hip_bf16.h>
#include <math.h>

#define SELU_SCALE 1.0507009873554805f
#define SELU_ALPHA 1.6732632423543772f

static constexpr int B_ = 16, T_ = 16, L_ = 512, H_ = 768;

typedef __bf16 bf16x8 __attribute__((ext_vector_type(8)));
typedef __bf16 bf16x4 __attribute__((ext_vector_type(4)));
typedef float  f32x4  __attribute__((ext_vector_type(4)));

__device__ __forceinline__ float bf_lo(unsigned u) { return __uint_as_float(u << 16); }
__device__ __forceinline__ float bf_hi(unsigned u) { return __uint_as_float(u & 0xFFFF0000u); }

__device__ __forceinline__ float selu_core(float x) {
    float e = fmaf(__expf(x), SELU_ALPHA, -SELU_ALPHA);
    return x > 0.0f ? x : e;
}

// ---------------- converts (float4 -> bf16x4) ----------------
__global__ __launch_bounds__(256) void cvt4_k(const float* __restrict__ in,
                                              __bf16* __restrict__ out, int n4) {
    int i = blockIdx.x * 256 + threadIdx.x;
    if (i < n4) {
        float4 f = ((const float4*)in)[i];
        bf16x4 o;
        o.x = (__bf16)f.x; o.y = (__bf16)f.y; o.z = (__bf16)f.z; o.w = (__bf16)f.w;
        ((bf16x4*)out)[i] = o;
    }
}

// W1 and W2 in one launch: blockIdx.y selects
__global__ __launch_bounds__(256) void cvtW_k(const float* __restrict__ w1,
                                              const float* __restrict__ w2,
                                              __bf16* __restrict__ o1,
                                              __bf16* __restrict__ o2) {
    int i = blockIdx.x * 256 + threadIdx.x;   // < 147456
    const float* src = blockIdx.y ? w2 : w1;
    __bf16* dst = blockIdx.y ? o2 : o1;
    float4 f = ((const float4*)src)[i];
    bf16x4 o;
    o.x = (__bf16)f.x; o.y = (__bf16)f.y; o.z = (__bf16)f.z; o.w = (__bf16)f.w;
    ((bf16x4*)dst)[i] = o;
}

// dj[bt,:] = bf16(decoder_out[b, Yindex[bt], :]) ; 192 threads, 4 elems each
__global__ __launch_bounds__(192) void gather_dj_k(const float* __restrict__ dec,
                                                   const int* __restrict__ Yi,
                                                   __bf16* __restrict__ djb) {
    int bt = blockIdx.x;
    int b  = bt >> 4;
    int y  = Yi[bt];
    const float4* src = (const float4*)(dec + ((size_t)(b * L_ + y)) * H_);
    bf16x4* dst = (bf16x4*)(djb + (size_t)bt * H_);
    float4 f = src[threadIdx.x];
    bf16x4 o;
    o.x = (__bf16)f.x; o.y = (__bf16)f.y; o.z = (__bf16)f.z; o.w = (__bf16)f.w;
    dst[threadIdx.x] = o;
}

// ---------------- staged NT GEMM: C[m][n] = sum_k A[m][k]*Bm[n][k] ----------------
// 128x128 block tile, BK=32, 4 waves (2x2) of 64x64, LDS staged via global_load_lds.
// LDS layout: row-major [row][32k] bf16, stride 64B -> matches wave-uniform-base +
// lane*16B DMA contract (lane i -> row i/4, kseg (i&3)*8).
__device__ __forceinline__ void load16_lds(const __bf16* g, __bf16* l) {
    __builtin_amdgcn_global_load_lds(
        (const __attribute__((address_space(1))) unsigned int*)g,
        (__attribute__((address_space(3))) unsigned int*)l, 16, 0, 0);
}

__global__ __launch_bounds__(256) void gemm_nt_bf16_k(
        const __bf16* __restrict__ A, const __bf16* __restrict__ Bm,
        __bf16* __restrict__ C, int M, int N, int K) {
    __shared__ __bf16 As[128 * 32];   // 8 KB
    __shared__ __bf16 Bs[128 * 32];   // 8 KB
    const int wave = threadIdx.x >> 6;
    const int lane = threadIdx.x & 63;
    const int m0 = blockIdx.x * 128, n0 = blockIdx.y * 128;
    const int wm = (wave >> 1) * 64, wn = (wave & 1) * 64;
    const int lr = lane & 15, q = lane >> 4;

    const int srow = wave * 32 + (lane >> 2);   // staging row this lane loads
    const int scol = (lane & 3) * 8;            // staging k-offset (8 bf16 = 16B)
    const __bf16* Ag = A  + (size_t)(m0 + srow) * K + scol;
    const __bf16* Bg = Bm + (size_t)(n0 + srow) * K + scol;
    __bf16* Asw = &As[(wave * 32) * 32];
    __bf16* Bsw = &Bs[(wave * 32) * 32];

    f32x4 acc[4][4] = {};

    for (int k0 = 0; k0 < K; k0 += 32) {
        load16_lds(Ag + k0,            Asw);
        load16_lds(Ag + 16 * K + k0,   Asw + 16 * 32);
        load16_lds(Bg + k0,            Bsw);
        load16_lds(Bg + 16 * K + k0,   Bsw + 16 * 32);
        __syncthreads();
        bf16x8 af[4], bfr[4];
#pragma unroll
        for (int i = 0; i < 4; ++i)
            af[i] = *(const bf16x8*)&As[(wm + i * 16 + lr) * 32 + q * 8];
#pragma unroll
        for (int j = 0; j < 4; ++j)
            bfr[j] = *(const bf16x8*)&Bs[(wn + j * 16 + lr) * 32 + q * 8];
#pragma unroll
        for (int i = 0; i < 4; ++i)
#pragma unroll
            for (int j = 0; j < 4; ++j)
                acc[i][j] = __builtin_amdgcn_mfma_f32_16x16x32_bf16(af[i], bfr[j], acc[i][j], 0, 0, 0);
        __syncthreads();
    }

#pragma unroll
    for (int i = 0; i < 4; ++i)
#pragma unroll
        for (int j = 0; j < 4; ++j)
#pragma unroll
            for (int r = 0; r < 4; ++r) {
                int row = m0 + wm + i * 16 + q * 4 + r;
                int col = n0 + wn + j * 16 + lr;
                C[(size_t)row * N + col] = (__bf16)acc[i][j][r];
            }
}

// ---------------- fused scores: per-lane (t,l), no shuffles ----------------
// grid (B, L/16), 256 threads: t = tid>>4, l = l0 + (tid&15).
// LDS: WE f32 [16][772] (49.4KB), WD bf16 [16 rows][388 dwords] (24.8KB).
__global__ __launch_bounds__(256) void scores_k(
        const __bf16* __restrict__ web, const __bf16* __restrict__ wdb,
        const float* __restrict__ V, const int* __restrict__ Xi,
        float* __restrict__ scores) {
    __shared__ float    we_s[16][772];
    __shared__ unsigned wd_s[16][388];

    const int b = blockIdx.x, l0 = blockIdx.y * 16;

    // fill WE (bf16 -> f32) : 16 rows x 96 chunks of 8 elems
    for (int c = threadIdx.x; c < 16 * 96; c += 256) {
        int r = c / 96, cc = c % 96;
        uint4 v = *(const uint4*)(web + ((size_t)(b * L_ + l0 + r)) * H_ + cc * 8);
        float4 f0, f1;
        f0.x = bf_lo(v.x); f0.y = bf_hi(v.x); f0.z = bf_lo(v.y); f0.w = bf_hi(v.y);
        f1.x = bf_lo(v.z); f1.y = bf_hi(v.z); f1.z = bf_lo(v.w); f1.w = bf_hi(v.w);
        *(float4*)&we_s[r][cc * 8]     = f0;
        *(float4*)&we_s[r][cc * 8 + 4] = f1;
    }
    // fill WD (raw bf16 copy)
    for (int c = threadIdx.x; c < 16 * 96; c += 256) {
        int r = c / 96, cc = c % 96;
        *(uint4*)&wd_s[r][cc * 4] = *(const uint4*)(wdb + ((size_t)(b * T_ + r)) * H_ + cc * 8);
    }
    __syncthreads();

    const int t = threadIdx.x >> 4;
    const int ls = threadIdx.x & 15;
    const int l = l0 + ls;
    const int X = Xi[b * T_ + t];
    if (!__any(l >= X)) return;   // whole wave masked (ref masks l < Xindex)

    float a0 = 0.f, a1 = 0.f, a2 = 0.f, a3 = 0.f;
#pragma unroll 4
    for (int h = 0; h < H_; h += 8) {
        float4 w0 = *(const float4*)&we_s[ls][h];
        float4 w1 = *(const float4*)&we_s[ls][h + 4];
        uint4  wd = *(const uint4*)&wd_s[t][h >> 1];
        float4 v0 = *(const float4*)(V + h);
        float4 v1 = *(const float4*)(V + h + 4);
        a0 = fmaf(selu_core(w0.x + bf_lo(wd.x)), v0.x, a0);
        a1 = fmaf(selu_core(w0.y + bf_hi(wd.x)), v0.y, a1);
        a2 = fmaf(selu_core(w0.z + bf_lo(wd.y)), v0.z, a2);
        a3 = fmaf(selu_core(w0.w + bf_hi(wd.y)), v0.w, a3);
        a0 = fmaf(selu_core(w1.x + bf_lo(wd.z)), v1.x, a0);
        a1 = fmaf(selu_core(w1.y + bf_hi(wd.z)), v1.y, a1);
        a2 = fmaf(selu_core(w1.z + bf_lo(wd.w)), v1.z, a2);
        a3 = fmaf(selu_core(w1.w + bf_hi(wd.w)), v1.w, a3);
    }
    float dot = SELU_SCALE * ((a0 + a1) + (a2 + a3));
    float sc  = dot > 0.0f ? SELU_SCALE * dot
                           : SELU_SCALE * SELU_ALPHA * (__expf(dot) - 1.0f);
    scores[((size_t)(b * T_ + t)) * L_ + l] = sc;
}

// ---------------- per-(b,t) masked logsumexp + gold ----------------
__global__ __launch_bounds__(64) void nll_k(
        const float* __restrict__ scores, const int* __restrict__ Xi,
        const int* __restrict__ Yi, float* __restrict__ gold) {
    const int bt = blockIdx.x;
    const int lane = threadIdx.x;
    const int X = Xi[bt];
    const int Y = Yi[bt];
    const float* row = scores + (size_t)bt * L_;

    float m = -INFINITY;
    for (int l = X + lane; l < L_; l += 64) m = fmaxf(m, row[l]);
#pragma unroll
    for (int off = 32; off > 0; off >>= 1) m = fmaxf(m, __shfl_xor(m, off));

    float s = 0.0f;
    for (int l = X + lane; l < L_; l += 64) s += expf(row[l] - m);
#pragma unroll
    for (int off = 32; off > 0; off >>= 1) s += __shfl_xor(s, off);

    if (lane == 0) gold[bt] = row[Y] - m - logf(s);
}

__global__ __launch_bounds__(256) void finalize_k(const float* __restrict__ gold,
                                                  float* __restrict__ out) {
    __shared__ float red[4];
    const int lane = threadIdx.x & 63, wave = threadIdx.x >> 6;
    float v = gold[threadIdx.x];
#pragma unroll
    for (int off = 32; off > 0; off >>= 1) v += __shfl_xor(v, off);
    if (lane == 0) red[wave] = v;
    __syncthreads();
    if (threadIdx.x == 0) out[0] = -(red[0] + red[1] + red[2] + red[3]) * (1.0f / 256.0f);
}

// ---------------- launch ----------------
extern "C" void kernel_launch(void* const* d_in, const int* in_sizes, int n_in,
                              void* d_out, int out_size, void* d_ws, size_t ws_size,
                              hipStream_t stream) {
    const float* hn  = (const float*)d_in[0];
    const float* dec = (const float*)d_in[1];
    const float* W1  = (const float*)d_in[2];
    const float* W2  = (const float*)d_in[3];
    const float* V   = (const float*)d_in[4];
    const int*   Xi  = (const int*)d_in[5];
    const int*   Yi  = (const int*)d_in[6];
    float* out = (float*)d_out;

    char* ws = (char*)d_ws;
    size_t off = 0;
    auto alloc = [&](size_t bytes) -> char* {
        char* p = ws + off;
        off += (bytes + 255) & ~(size_t)255;
        return p;
    };
    __bf16* hnb    = (__bf16*)alloc((size_t)B_ * L_ * H_ * 2);
    __bf16* w1b    = (__bf16*)alloc((size_t)H_ * H_ * 2);
    __bf16* w2b    = (__bf16*)alloc((size_t)H_ * H_ * 2);
    __bf16* djb    = (__bf16*)alloc((size_t)B_ * T_ * H_ * 2);
    __bf16* web    = (__bf16*)alloc((size_t)B_ * L_ * H_ * 2);
    __bf16* wdb    = (__bf16*)alloc((size_t)B_ * T_ * H_ * 2);
    float*  scores = (float*)alloc((size_t)B_ * T_ * L_ * 4);
    float*  gold   = (float*)alloc((size_t)B_ * T_ * 4);

    cvt4_k<<<(B_ * L_ * H_ / 4 + 255) / 256, 256, 0, stream>>>(hn, hnb, B_ * L_ * H_ / 4);
    cvtW_k<<<dim3(H_ * H_ / 4 / 256, 2), 256, 0, stream>>>(W1, W2, w1b, w2b);
    gather_dj_k<<<B_ * T_, 192, 0, stream>>>(dec, Yi, djb);

    // WE = hn @ W1^T : M=8192, N=768, K=768
    gemm_nt_bf16_k<<<dim3(64, 6), 256, 0, stream>>>(hnb, w1b, web, B_ * L_, H_, H_);
    // WD = dj @ W2^T : M=256, N=768, K=768
    gemm_nt_bf16_k<<<dim3(2, 6), 256, 0, stream>>>(djb, w2b, wdb, B_ * T_, H_, H_);

    scores_k<<<dim3(B_, L_ / 16), 256, 0, stream>>>(web, wdb, V, Xi, scores);
    nll_k<<<B_ * T_, 64, 0, stream>>>(scores, Xi, Yi, gold);
    finalize_k<<<1, 256, 0, stream>>>(gold, out);
}

// Round 3
// 161.651 us; speedup vs baseline: 1.4628x; 1.0992x over previous
//
#include <hip/hip_runtime.h>
#include <hip/hip_bf16.h>
#include <math.h>

#define SELU_SCALE 1.0507009873554805f
#define SELU_ALPHA 1.6732632423543772f

static constexpr int B_ = 16, T_ = 16, L_ = 512, H_ = 768;

typedef __bf16 bf16x8 __attribute__((ext_vector_type(8)));
typedef __bf16 bf16x4 __attribute__((ext_vector_type(4)));
typedef float  f32x4  __attribute__((ext_vector_type(4)));

__device__ __forceinline__ float bf_lo(unsigned u) { return __uint_as_float(u << 16); }
__device__ __forceinline__ float bf_hi(unsigned u) { return __uint_as_float(u & 0xFFFF0000u); }

__device__ __forceinline__ float selu_core(float x) {
    float e = fmaf(__expf(x), SELU_ALPHA, -SELU_ALPHA);
    return x > 0.0f ? x : e;
}

__device__ __forceinline__ bf16x4 cvt4(float4 f) {
    bf16x4 o;
    o.x = (__bf16)f.x; o.y = (__bf16)f.y; o.z = (__bf16)f.z; o.w = (__bf16)f.w;
    return o;
}

// ---------------- fused prep: hn->bf16, W1->bf16, W2->bf16, dj gather+cvt -------
// flat float4-granular work: [0,N0) hn, [N0,N1) W1, [N1,N2) W2, [N2,N3) dj
__global__ __launch_bounds__(256) void prep_k(
        const float* __restrict__ hn, const float* __restrict__ w1,
        const float* __restrict__ w2, const float* __restrict__ dec,
        const int* __restrict__ Yi,
        __bf16* __restrict__ hnb, __bf16* __restrict__ w1b,
        __bf16* __restrict__ w2b, __bf16* __restrict__ djb) {
    const int N0 = B_ * L_ * H_ / 4;           // 1572864
    const int NW = H_ * H_ / 4;                // 147456
    const int N1 = N0 + NW, N2 = N1 + NW;
    int i = blockIdx.x * 256 + threadIdx.x;
    if (i < N0) {
        ((bf16x4*)hnb)[i] = cvt4(((const float4*)hn)[i]);
    } else if (i < N1) {
        int j = i - N0;
        ((bf16x4*)w1b)[j] = cvt4(((const float4*)w1)[j]);
    } else if (i < N2) {
        int j = i - N1;
        ((bf16x4*)w2b)[j] = cvt4(((const float4*)w2)[j]);
    } else {
        int j = i - N2;                        // < 256*192
        int bt = j / 192, c = j % 192;
        int b = bt >> 4;
        int y = Yi[bt];
        ((bf16x4*)djb)[bt * 192 + c] =
            cvt4(((const float4*)dec)[(b * L_ + y) * 192 + c]);
    }
}

// ---------------- fused NT GEMM (WE + WD): C[m][n] = sum_k A[m][k]*B[n][k] ------
// BM=64, BN=128, BK=32, K=N=768. 4 waves of 32x64 (2x4 MFMA 16x16x32).
// LDS k-segment XOR swizzle: seg_stored = q ^ ((row ^ (row>>2)) & 3) -> frag
// ds_read_b128 is 2-way banked (free) while keeping the global_load_lds
// lane*16B contract intact (we swizzle WHICH column a lane fetches).
__device__ __forceinline__ void load16_lds(const __bf16* g, __bf16* l) {
    __builtin_amdgcn_global_load_lds(
        (const __attribute__((address_space(1))) unsigned int*)g,
        (__attribute__((address_space(3))) unsigned int*)l, 16, 0, 0);
}
__device__ __forceinline__ int sw3(int row) { return (row ^ (row >> 2)) & 3; }

__global__ __launch_bounds__(256) void gemm_k(
        const __bf16* __restrict__ hnb, const __bf16* __restrict__ djb,
        const __bf16* __restrict__ w1b, const __bf16* __restrict__ w2b,
        __bf16* __restrict__ web, __bf16* __restrict__ wdb) {
    __shared__ __bf16 As[64 * 32];    // 4 KB
    __shared__ __bf16 Bs[128 * 32];   // 8 KB

    int bx = blockIdx.x;
    const __bf16* A; const __bf16* Bw; __bf16* C;
    if (bx < 768) { A = hnb; Bw = w1b; C = web; }
    else          { bx -= 768; A = djb; Bw = w2b; C = wdb; }
    const int m0 = (bx / 6) * 64, n0 = (bx % 6) * 128;

    const int wave = threadIdx.x >> 6;
    const int lane = threadIdx.x & 63;
    const int wm = (wave >> 1) * 32, wn = (wave & 1) * 64;
    const int lr = lane & 15, q = lane >> 4;

    // staging assignment (fixed by DMA contract): lane -> slot (row, s=lane&3)
    const int arow = wave * 16 + (lane >> 2);          // As local row
    const int acol = ((lane & 3) ^ sw3(arow)) * 8;     // swizzled logical k-seg
    const int brow0 = wave * 32 + (lane >> 2);
    const int bcol0 = ((lane & 3) ^ sw3(brow0)) * 8;
    const int brow1 = brow0 + 16;
    const int bcol1 = ((lane & 3) ^ sw3(brow1)) * 8;
    const __bf16* Ag  = A  + (size_t)(m0 + arow)  * 768 + acol;
    const __bf16* Bg0 = Bw + (size_t)(n0 + brow0) * 768 + bcol0;
    const __bf16* Bg1 = Bw + (size_t)(n0 + brow1) * 768 + bcol1;
    __bf16* Asw = &As[wave * 16 * 32];
    __bf16* Bsw0 = &Bs[wave * 32 * 32];
    __bf16* Bsw1 = Bsw0 + 16 * 32;

    // frag read addresses (swizzled)
    int aoff[2], boff[4];
#pragma unroll
    for (int i = 0; i < 2; ++i) {
        int r = wm + i * 16 + lr;
        aoff[i] = r * 32 + ((q ^ sw3(r)) & 3) * 8;
    }
#pragma unroll
    for (int j = 0; j < 4; ++j) {
        int r = wn + j * 16 + lr;
        boff[j] = r * 32 + ((q ^ sw3(r)) & 3) * 8;
    }

    f32x4 acc[2][4] = {};

    for (int k0 = 0; k0 < 768; k0 += 32) {
        load16_lds(Ag  + k0, Asw);
        load16_lds(Bg0 + k0, Bsw0);
        load16_lds(Bg1 + k0, Bsw1);
        __syncthreads();
        bf16x8 af[2], bfr[4];
#pragma unroll
        for (int i = 0; i < 2; ++i) af[i]  = *(const bf16x8*)&As[aoff[i]];
#pragma unroll
        for (int j = 0; j < 4; ++j) bfr[j] = *(const bf16x8*)&Bs[boff[j]];
#pragma unroll
        for (int i = 0; i < 2; ++i)
#pragma unroll
            for (int j = 0; j < 4; ++j)
                acc[i][j] = __builtin_amdgcn_mfma_f32_16x16x32_bf16(af[i], bfr[j], acc[i][j], 0, 0, 0);
        __syncthreads();
    }

#pragma unroll
    for (int i = 0; i < 2; ++i)
#pragma unroll
        for (int j = 0; j < 4; ++j)
#pragma unroll
            for (int r = 0; r < 4; ++r) {
                int row = m0 + wm + i * 16 + q * 4 + r;
                int col = n0 + wn + j * 16 + lr;
                C[(size_t)row * 768 + col] = (__bf16)acc[i][j][r];
            }
}

// ---------------- fused scores: per-lane (t,l), no shuffles ----------------
__global__ __launch_bounds__(256) void scores_k(
        const __bf16* __restrict__ web, const __bf16* __restrict__ wdb,
        const float* __restrict__ V, const int* __restrict__ Xi,
        float* __restrict__ scores) {
    __shared__ float    we_s[16][772];
    __shared__ unsigned wd_s[16][388];
    __shared__ float    v_s[768];

    const int b = blockIdx.x, l0 = blockIdx.y * 16;

    for (int c = threadIdx.x; c < 16 * 96; c += 256) {
        int r = c / 96, cc = c % 96;
        uint4 v = *(const uint4*)(web + ((size_t)(b * L_ + l0 + r)) * H_ + cc * 8);
        float4 f0, f1;
        f0.x = bf_lo(v.x); f0.y = bf_hi(v.x); f0.z = bf_lo(v.y); f0.w = bf_hi(v.y);
        f1.x = bf_lo(v.z); f1.y = bf_hi(v.z); f1.z = bf_lo(v.w); f1.w = bf_hi(v.w);
        *(float4*)&we_s[r][cc * 8]     = f0;
        *(float4*)&we_s[r][cc * 8 + 4] = f1;
    }
    for (int c = threadIdx.x; c < 16 * 96; c += 256) {
        int r = c / 96, cc = c % 96;
        *(uint4*)&wd_s[r][cc * 4] = *(const uint4*)(wdb + ((size_t)(b * T_ + r)) * H_ + cc * 8);
    }
    if (threadIdx.x < 192) *(float4*)&v_s[threadIdx.x * 4] = ((const float4*)V)[threadIdx.x];
    __syncthreads();

    const int t = threadIdx.x >> 4;
    const int ls = threadIdx.x & 15;
    const int l = l0 + ls;
    const int X = Xi[b * T_ + t];
    if (!__any(l >= X)) return;

    float a0 = 0.f, a1 = 0.f, a2 = 0.f, a3 = 0.f;
#pragma unroll 4
    for (int h = 0; h < H_; h += 8) {
        float4 w0 = *(const float4*)&we_s[ls][h];
        float4 w1 = *(const float4*)&we_s[ls][h + 4];
        uint4  wd = *(const uint4*)&wd_s[t][h >> 1];
        float4 v0 = *(const float4*)&v_s[h];
        float4 v1 = *(const float4*)&v_s[h + 4];
        a0 = fmaf(selu_core(w0.x + bf_lo(wd.x)), v0.x, a0);
        a1 = fmaf(selu_core(w0.y + bf_hi(wd.x)), v0.y, a1);
        a2 = fmaf(selu_core(w0.z + bf_lo(wd.y)), v0.z, a2);
        a3 = fmaf(selu_core(w0.w + bf_hi(wd.y)), v0.w, a3);
        a0 = fmaf(selu_core(w1.x + bf_lo(wd.z)), v1.x, a0);
        a1 = fmaf(selu_core(w1.y + bf_hi(wd.z)), v1.y, a1);
        a2 = fmaf(selu_core(w1.z + bf_lo(wd.w)), v1.z, a2);
        a3 = fmaf(selu_core(w1.w + bf_hi(wd.w)), v1.w, a3);
    }
    float dot = SELU_SCALE * ((a0 + a1) + (a2 + a3));
    float sc  = dot > 0.0f ? SELU_SCALE * dot
                           : SELU_SCALE * SELU_ALPHA * (__expf(dot) - 1.0f);
    scores[((size_t)(b * T_ + t)) * L_ + l] = sc;
}

// ---------------- per-(b,t) masked logsumexp + gold + mean (atomic) -------------
__global__ __launch_bounds__(64) void loss_k(
        const float* __restrict__ scores, const int* __restrict__ Xi,
        const int* __restrict__ Yi, float* __restrict__ out) {
    const int bt = blockIdx.x;
    const int lane = threadIdx.x;
    const int X = Xi[bt];
    const int Y = Yi[bt];
    const float* row = scores + (size_t)bt * L_;

    float m = -INFINITY;
    for (int l = X + lane; l < L_; l += 64) m = fmaxf(m, row[l]);
#pragma unroll
    for (int off = 32; off > 0; off >>= 1) m = fmaxf(m, __shfl_xor(m, off));

    float s = 0.0f;
    for (int l = X + lane; l < L_; l += 64) s += expf(row[l] - m);
#pragma unroll
    for (int off = 32; off > 0; off >>= 1) s += __shfl_xor(s, off);

    if (lane == 0)
        atomicAdd(out, (m + logf(s) - row[Y]) * (1.0f / (B_ * T_)));
}

// ---------------- launch ----------------
extern "C" void kernel_launch(void* const* d_in, const int* in_sizes, int n_in,
                              void* d_out, int out_size, void* d_ws, size_t ws_size,
                              hipStream_t stream) {
    const float* hn  = (const float*)d_in[0];
    const float* dec = (const float*)d_in[1];
    const float* W1  = (const float*)d_in[2];
    const float* W2  = (const float*)d_in[3];
    const float* V   = (const float*)d_in[4];
    const int*   Xi  = (const int*)d_in[5];
    const int*   Yi  = (const int*)d_in[6];
    float* out = (float*)d_out;

    char* ws = (char*)d_ws;
    size_t off = 0;
    auto alloc = [&](size_t bytes) -> char* {
        char* p = ws + off;
        off += (bytes + 255) & ~(size_t)255;
        return p;
    };
    __bf16* hnb    = (__bf16*)alloc((size_t)B_ * L_ * H_ * 2);
    __bf16* w1b    = (__bf16*)alloc((size_t)H_ * H_ * 2);
    __bf16* w2b    = (__bf16*)alloc((size_t)H_ * H_ * 2);
    __bf16* djb    = (__bf16*)alloc((size_t)B_ * T_ * H_ * 2);
    __bf16* web    = (__bf16*)alloc((size_t)B_ * L_ * H_ * 2);
    __bf16* wdb    = (__bf16*)alloc((size_t)B_ * T_ * H_ * 2);
    float*  scores = (float*)alloc((size_t)B_ * T_ * L_ * 4);

    hipMemsetAsync(out, 0, sizeof(float), stream);

    // prep: (1572864 + 2*147456 + 49152) / 256 = 7488 blocks
    prep_k<<<7488, 256, 0, stream>>>(hn, W1, W2, dec, Yi, hnb, w1b, w2b, djb);

    // WE (768 blocks) + WD (24 blocks) fused
    gemm_k<<<792, 256, 0, stream>>>(hnb, djb, w1b, w2b, web, wdb);

    scores_k<<<dim3(B_, L_ / 16), 256, 0, stream>>>(web, wdb, V, Xi, scores);
    loss_k<<<B_ * T_, 64, 0, stream>>>(scores, Xi, Yi, out);
}